// Round 1
// baseline (2762.205 us; speedup 1.0000x reference)
//
#include <hip/hip_runtime.h>
#include <hip/hip_bf16.h>
#include <math.h>

#define BN_EPS 1e-5f

// ---------- helpers ----------
static __device__ __forceinline__ unsigned short f2bf(float f) {
  unsigned int u = __float_as_uint(f);
  unsigned int r = (u + 0x7FFFu + ((u >> 16) & 1u)) >> 16;   // RNE
  return (unsigned short)r;
}
static __device__ __forceinline__ float bf2f(unsigned short v) {
  return __uint_as_float(((unsigned int)v) << 16);
}
static __device__ __forceinline__ float sigmoidf_(float x) {
  return 1.0f / (1.0f + __expf(-x));
}
static __device__ __forceinline__ float softplusf_(float x) {
  // logaddexp(x, 0) — numerically stable, matches jax.nn.softplus
  return fmaxf(x, 0.0f) + log1pf(__expf(-fabsf(x)));
}

// ---------- kernels ----------

// zero degree array + stats accumulators
__global__ void k_zero(int* __restrict__ deg, float* __restrict__ stats, int N) {
  int stride = gridDim.x * blockDim.x;
  int i = blockIdx.x * blockDim.x + threadIdx.x;
  for (int j = i; j < N; j += stride) deg[j] = 0;
  for (int j = i; j < 768; j += stride) stats[j] = 0.f;
}

// degree count over src = edge_index[0]
__global__ void k_deg(const int* __restrict__ ei, int* __restrict__ deg, int E) {
  int e = blockIdx.x * blockDim.x + threadIdx.x;
  if (e < E) atomicAdd(&deg[ei[e]], 1);
}

// exclusive scan of deg -> offs, and copy -> cursor. Single block of 1024.
__global__ __launch_bounds__(1024) void k_scan(const int* __restrict__ deg,
                                               int* __restrict__ offs,
                                               int* __restrict__ cursor, int N) {
  __shared__ int wsum[16];
  __shared__ int carry_s;
  int tid = threadIdx.x;
  int lane = tid & 63, wv = tid >> 6;
  if (tid == 0) carry_s = 0;
  __syncthreads();
  for (int base = 0; base < N; base += 1024) {
    int i = base + tid;
    int v = (i < N) ? deg[i] : 0;
    int x = v;
    #pragma unroll
    for (int off = 1; off < 64; off <<= 1) {
      int t = __shfl_up(x, off, 64);
      if (lane >= off) x += t;
    }
    if (lane == 63) wsum[wv] = x;
    __syncthreads();
    if (wv == 0 && lane < 16) {
      int y = wsum[lane];
      #pragma unroll
      for (int off = 1; off < 16; off <<= 1) {
        int t = __shfl_up(y, off, 64);
        if (lane >= off) y += t;
      }
      wsum[lane] = y;  // inclusive over waves
    }
    __syncthreads();
    int woff = (wv == 0) ? 0 : wsum[wv - 1];
    int carry = carry_s;
    int incl = woff + x;
    if (i < N) { int o = carry + incl - v; offs[i] = o; cursor[i] = o; }
    __syncthreads();                 // everyone read carry_s
    if (tid == 1023) carry_s = carry + incl;
    __syncthreads();
  }
}

// P[n, 0:256] = x[n,:] @ W[0:128,:]; P[n, 256:512] = x[n,:] @ W[128:256,:]
// grid (ceil(N/64), 8); block 256 (16 colgrp x 16 rowgrp, 4x4 per thread)
__global__ __launch_bounds__(256) void k_pgemm(const float* __restrict__ x,
                                               const float* __restrict__ W,
                                               float* __restrict__ P, int N) {
  __shared__ float xs[64][132];       // +4 pad: conflict-free b128 reads
  int row0 = blockIdx.x * 64;
  int bn = blockIdx.y;                // 0..7
  int tid = threadIdx.x;
  for (int idx = tid; idx < 2048; idx += 256) {
    int r = idx >> 5;
    int c4 = (idx & 31) << 2;
    int gr = row0 + r;
    float4 v = make_float4(0.f, 0.f, 0.f, 0.f);
    if (gr < N) v = *(const float4*)(x + (size_t)gr * 128 + c4);
    *(float4*)(&xs[r][c4]) = v;
  }
  __syncthreads();
  int cg = tid & 15, rg = tid >> 4;
  int r0 = rg * 4;
  int jloc = (bn & 3) * 64 + cg * 4;
  const float* wb = W + (size_t)((bn >> 2) ? 128 * 256 : 0) + jloc;
  float acc[4][4] = {};
  for (int k = 0; k < 128; k += 4) {
    float a[4][4], w[4][4];
    #pragma unroll
    for (int i = 0; i < 4; ++i) *(float4*)a[i] = *(const float4*)&xs[r0 + i][k];
    #pragma unroll
    for (int t = 0; t < 4; ++t) *(float4*)w[t] = *(const float4*)(wb + (size_t)(k + t) * 256);
    #pragma unroll
    for (int i = 0; i < 4; ++i)
      #pragma unroll
      for (int t = 0; t < 4; ++t)
        #pragma unroll
        for (int j = 0; j < 4; ++j)
          acc[i][j] += a[i][t] * w[t][j];
  }
  int colbase = ((bn >> 2) ? 256 : 0) + jloc;
  #pragma unroll
  for (int i = 0; i < 4; ++i) {
    int r = row0 + r0 + i;
    if (r < N) *(float4*)(P + (size_t)r * 512 + colbase) = *(float4*)acc[i];
  }
}

// Phase 1: per 64-edge tile: q = ea@W3; gated = P1[src]+P2[dst]+q+b;
// accumulate BN1 sums; store gated (bf16) at CSR slot.
__global__ __launch_bounds__(256) void k_phase1(
    const float* __restrict__ ea, const int* __restrict__ ei,
    const float* __restrict__ W, const float* __restrict__ bias,
    const float* __restrict__ P, unsigned short* __restrict__ gated,
    int* __restrict__ cursor, float* __restrict__ stats, int E) {
  __shared__ float ea_s[64][68];
  __shared__ float w3_s[64][68];
  __shared__ int ssrc[64], sdst[64], spos[64];
  __shared__ float lsum[64], lsq[64];
  int tid = threadIdx.x;
  int e0 = blockIdx.x * 64;
  if (tid < 64) {
    int e = e0 + tid;
    int s = 0, d = 0, p = 0;
    if (e < E) {
      s = ei[e]; d = ei[E + e];
      p = atomicAdd(&cursor[s], 1);
    }
    ssrc[tid] = s; sdst[tid] = d; spos[tid] = p;
  }
  for (int idx = tid; idx < 1024; idx += 256) {
    int r = idx >> 4;
    int c4 = (idx & 15) << 2;
    float4 v = make_float4(0.f, 0.f, 0.f, 0.f);
    if (e0 + r < E) v = *(const float4*)(ea + (size_t)(e0 + r) * 64 + c4);
    *(float4*)(&ea_s[r][c4]) = v;
  }
  int cg = tid & 15, rg = tid >> 4;
  int r0 = rg * 4, c0 = cg * 4;
  float* sum1 = stats;
  float* sq1 = stats + 256;
  for (int cc = 0; cc < 4; ++cc) {
    int jb = cc * 64;
    __syncthreads();                       // ea_s/ids ready; prev w3_s readers done
    for (int idx = tid; idx < 1024; idx += 256) {
      int k = idx >> 4;
      int j4 = (idx & 15) << 2;
      *(float4*)(&w3_s[k][j4]) = *(const float4*)(W + (size_t)(256 + k) * 256 + jb + j4);
    }
    if (tid < 64) { lsum[tid] = 0.f; lsq[tid] = 0.f; }
    __syncthreads();
    float acc[4][4] = {};
    for (int k = 0; k < 64; k += 4) {
      float a[4][4], w[4][4];
      #pragma unroll
      for (int i = 0; i < 4; ++i) *(float4*)a[i] = *(const float4*)&ea_s[r0 + i][k];
      #pragma unroll
      for (int t = 0; t < 4; ++t) *(float4*)w[t] = *(const float4*)&w3_s[k + t][c0];
      #pragma unroll
      for (int i = 0; i < 4; ++i)
        #pragma unroll
        for (int t = 0; t < 4; ++t)
          #pragma unroll
          for (int j = 0; j < 4; ++j)
            acc[i][j] += a[i][t] * w[t][j];
    }
    float4 bv = *(const float4*)(bias + jb + c0);
    float ls[4] = {0.f, 0.f, 0.f, 0.f}, lq[4] = {0.f, 0.f, 0.f, 0.f};
    #pragma unroll
    for (int i = 0; i < 4; ++i) {
      int r = r0 + i;
      int e = e0 + r;
      if (e < E) {
        float4 p1 = *(const float4*)(P + (size_t)ssrc[r] * 512 + jb + c0);
        float4 p2 = *(const float4*)(P + (size_t)sdst[r] * 512 + 256 + jb + c0);
        float g0 = acc[i][0] + p1.x + p2.x + bv.x;
        float g1 = acc[i][1] + p1.y + p2.y + bv.y;
        float g2 = acc[i][2] + p1.z + p2.z + bv.z;
        float g3 = acc[i][3] + p1.w + p2.w + bv.w;
        ls[0] += g0; lq[0] += g0 * g0;
        ls[1] += g1; lq[1] += g1 * g1;
        ls[2] += g2; lq[2] += g2 * g2;
        ls[3] += g3; lq[3] += g3 * g3;
        unsigned int lo = (unsigned int)f2bf(g0) | ((unsigned int)f2bf(g1) << 16);
        unsigned int hi = (unsigned int)f2bf(g2) | ((unsigned int)f2bf(g3) << 16);
        *(uint2*)(gated + (size_t)spos[r] * 256 + jb + c0) = make_uint2(lo, hi);
      }
    }
    #pragma unroll
    for (int j = 0; j < 4; ++j) {
      atomicAdd(&lsum[c0 + j], ls[j]);
      atomicAdd(&lsq[c0 + j], lq[j]);
    }
    __syncthreads();
    if (tid < 64) {
      atomicAdd(&sum1[jb + tid], lsum[tid]);
      atomicAdd(&sq1[jb + tid], lsq[tid]);
    }
  }
}

// finalize BN1: scale/shift per column
__global__ void k_bn1fin(float* __restrict__ stats, const float* __restrict__ g1,
                         const float* __restrict__ b1, float Einv) {
  int j = threadIdx.x;   // 256 threads
  float mu = stats[j] * Einv;
  float var = stats[256 + j] * Einv - mu * mu;
  float s = g1[j] * rsqrtf(var + BN_EPS);
  stats[768 + j] = s;
  stats[1024 + j] = b1[j] - mu * s;
}

// Phase 2: one wave per node: reduce its CSR run of gated rows -> summed (in d_out)
__global__ __launch_bounds__(256) void k_phase2(
    const unsigned short* __restrict__ gated,
    const int* __restrict__ offs, const int* __restrict__ deg,
    const float* __restrict__ stats, float* __restrict__ out, int N) {
  int wid = (blockIdx.x * 256 + threadIdx.x) >> 6;
  int lane = threadIdx.x & 63;
  if (wid >= N) return;
  const float* scale1 = stats + 768;
  const float* shift1 = stats + 1024;
  int c0 = lane * 2;
  float sf0 = scale1[c0], sf1 = scale1[c0 + 1];
  float hf0 = shift1[c0], hf1 = shift1[c0 + 1];
  float sc0 = scale1[128 + c0], sc1 = scale1[128 + c0 + 1];
  float hc0 = shift1[128 + c0], hc1 = shift1[128 + c0 + 1];
  int st = offs[wid], d = deg[wid];
  const unsigned short* rowp = gated + (size_t)st * 256;
  float a0 = 0.f, a1 = 0.f;
  for (int i = 0; i < d; ++i) {
    unsigned int fw = *(const unsigned int*)(rowp + c0);
    unsigned int cw = *(const unsigned int*)(rowp + 128 + c0);
    float f0 = bf2f((unsigned short)(fw & 0xFFFFu)) * sf0 + hf0;
    float f1 = bf2f((unsigned short)(fw >> 16)) * sf1 + hf1;
    float q0 = bf2f((unsigned short)(cw & 0xFFFFu)) * sc0 + hc0;
    float q1 = bf2f((unsigned short)(cw >> 16)) * sc1 + hc1;
    a0 += sigmoidf_(f0) * softplusf_(q0);
    a1 += sigmoidf_(f1) * softplusf_(q1);
    rowp += 256;
  }
  *(float2*)(out + (size_t)wid * 128 + c0) = make_float2(a0, a1);
}

// BN2 stats over summed (= d_out)
__global__ __launch_bounds__(256) void k_bn2stats(const float* __restrict__ out,
                                                  float* __restrict__ stats, int N) {
  float* sum2 = stats + 512;
  float* sq2 = stats + 640;
  __shared__ float s_[128], q_[128];
  int c = threadIdx.x & 127, h = threadIdx.x >> 7;
  float s = 0.f, q = 0.f;
  for (int r = blockIdx.x * 2 + h; r < N; r += gridDim.x * 2) {
    float v = out[(size_t)r * 128 + c];
    s += v; q += v * v;
  }
  if (h == 0) { s_[c] = s; q_[c] = q; }
  __syncthreads();
  if (h == 1) { s_[c] += s; q_[c] += q; }
  __syncthreads();
  if (h == 0) { atomicAdd(&sum2[c], s_[c]); atomicAdd(&sq2[c], q_[c]); }
}

// BN2 normalize in place
__global__ __launch_bounds__(256) void k_bn2norm(float* __restrict__ out,
                                                 const float* __restrict__ stats,
                                                 const float* __restrict__ g2,
                                                 const float* __restrict__ b2, int N) {
  const float* sum2 = stats + 512;
  const float* sq2 = stats + 640;
  float Ninv = 1.0f / (float)N;
  size_t total = (size_t)N * 32;   // float4 count
  for (size_t i = (size_t)blockIdx.x * blockDim.x + threadIdx.x; i < total;
       i += (size_t)gridDim.x * blockDim.x) {
    float4 v = *((const float4*)out + i);
    int c = (int)((i & 31) << 2);
    float r[4] = {v.x, v.y, v.z, v.w};
    #pragma unroll
    for (int j = 0; j < 4; ++j) {
      float mu = sum2[c + j] * Ninv;
      float var = sq2[c + j] * Ninv - mu * mu;
      float sc = g2[c + j] * rsqrtf(var + BN_EPS);
      r[j] = (r[j] - mu) * sc + b2[c + j];
    }
    *((float4*)out + i) = make_float4(r[0], r[1], r[2], r[3]);
  }
}

// ---------- launch ----------
extern "C" void kernel_launch(void* const* d_in, const int* in_sizes, int n_in,
                              void* d_out, int out_size, void* d_ws, size_t ws_size,
                              hipStream_t stream) {
  (void)n_in; (void)out_size;
  const float* x  = (const float*)d_in[0];
  const int*   ei = (const int*)d_in[1];
  const float* ea = (const float*)d_in[2];
  const float* W  = (const float*)d_in[3];
  const float* b  = (const float*)d_in[4];
  const float* g1 = (const float*)d_in[5];
  const float* b1 = (const float*)d_in[6];
  const float* g2 = (const float*)d_in[7];
  const float* b2 = (const float*)d_in[8];
  int N = in_sizes[0] / 128;
  int E = in_sizes[1] / 2;
  float* out = (float*)d_out;

  // ws layout
  char* base = (char*)d_ws;
  size_t off = 0;
  auto take = [&](size_t bytes) {
    size_t o = off;
    off = (off + bytes + 255) & ~(size_t)255;
    return o;
  };
  size_t oP      = take((size_t)N * 512 * sizeof(float));
  size_t oGated  = take((size_t)E * 256 * sizeof(unsigned short));
  size_t oDeg    = take((size_t)N * sizeof(int));
  size_t oOffs   = take((size_t)N * sizeof(int));
  size_t oCur    = take((size_t)N * sizeof(int));
  size_t oStats  = take(2048 * sizeof(float));
  if (off > ws_size) return;  // insufficient workspace — fail loudly via validation

  float* P = (float*)(base + oP);
  unsigned short* gated = (unsigned short*)(base + oGated);
  int* deg = (int*)(base + oDeg);
  int* offs = (int*)(base + oOffs);
  int* cursor = (int*)(base + oCur);
  float* stats = (float*)(base + oStats);

  k_zero<<<256, 256, 0, stream>>>(deg, stats, N);
  k_deg<<<(E + 255) / 256, 256, 0, stream>>>(ei, deg, E);
  k_scan<<<1, 1024, 0, stream>>>(deg, offs, cursor, N);
  k_pgemm<<<dim3((N + 63) / 64, 8), 256, 0, stream>>>(x, W, P, N);
  k_phase1<<<(E + 63) / 64, 256, 0, stream>>>(ea, ei, W, b, P, gated, cursor, stats, E);
  k_bn1fin<<<1, 256, 0, stream>>>(stats, g1, b1, 1.0f / (float)E);
  k_phase2<<<(N + 3) / 4, 256, 0, stream>>>(gated, offs, deg, stats, out, N);
  k_bn2stats<<<512, 256, 0, stream>>>(out, stats, N);
  k_bn2norm<<<1024, 256, 0, stream>>>(out, stats, g2, b2, N);
}

// Round 2
// 1384.977 us; speedup vs baseline: 1.9944x; 1.9944x over previous
//
#include <hip/hip_runtime.h>
#include <hip/hip_bf16.h>
#include <math.h>

#define BN_EPS 1e-5f

typedef __bf16 bf8 __attribute__((ext_vector_type(8)));
typedef unsigned short us8 __attribute__((ext_vector_type(8)));
typedef float f32x4 __attribute__((ext_vector_type(4)));

// ---------- helpers ----------
static __device__ __forceinline__ unsigned short f2bf(float f) {
  unsigned int u = __float_as_uint(f);
  unsigned int r = (u + 0x7FFFu + ((u >> 16) & 1u)) >> 16;   // RNE
  return (unsigned short)r;
}
static __device__ __forceinline__ float bf2f(unsigned short v) {
  return __uint_as_float(((unsigned int)v) << 16);
}
static __device__ __forceinline__ float sigmoidf_(float x) {
  return 1.0f / (1.0f + __expf(-x));
}
static __device__ __forceinline__ float softplusf_(float x) {
  return fmaxf(x, 0.0f) + log1pf(__expf(-fabsf(x)));
}

// ---------- kernels ----------

// zero degree array + stats accumulators
__global__ void k_zero(int* __restrict__ deg, float* __restrict__ stats, int N) {
  int stride = gridDim.x * blockDim.x;
  int i = blockIdx.x * blockDim.x + threadIdx.x;
  for (int j = i; j < N; j += stride) deg[j] = 0;
  for (int j = i; j < 768; j += stride) stats[j] = 0.f;
}

// degree count over src = edge_index[0]
__global__ void k_deg(const int* __restrict__ ei, int* __restrict__ deg, int E) {
  int e = blockIdx.x * blockDim.x + threadIdx.x;
  if (e < E) atomicAdd(&deg[ei[e]], 1);
}

// exclusive scan of deg -> offs, and copy -> cursor. Single block of 1024.
__global__ __launch_bounds__(1024) void k_scan(const int* __restrict__ deg,
                                               int* __restrict__ offs,
                                               int* __restrict__ cursor, int N) {
  __shared__ int wsum[16];
  __shared__ int carry_s;
  int tid = threadIdx.x;
  int lane = tid & 63, wv = tid >> 6;
  if (tid == 0) carry_s = 0;
  __syncthreads();
  for (int base = 0; base < N; base += 1024) {
    int i = base + tid;
    int v = (i < N) ? deg[i] : 0;
    int x = v;
    #pragma unroll
    for (int off = 1; off < 64; off <<= 1) {
      int t = __shfl_up(x, off, 64);
      if (lane >= off) x += t;
    }
    if (lane == 63) wsum[wv] = x;
    __syncthreads();
    if (wv == 0 && lane < 16) {
      int y = wsum[lane];
      #pragma unroll
      for (int off = 1; off < 16; off <<= 1) {
        int t = __shfl_up(y, off, 64);
        if (lane >= off) y += t;
      }
      wsum[lane] = y;  // inclusive over waves
    }
    __syncthreads();
    int woff = (wv == 0) ? 0 : wsum[wv - 1];
    int carry = carry_s;
    int incl = woff + x;
    if (i < N) { int o = carry + incl - v; offs[i] = o; cursor[i] = o; }
    __syncthreads();
    if (tid == 1023) carry_s = carry + incl;
    __syncthreads();
  }
}

// W [320][256] fp32 -> WT [256][320] bf16 (coalesced read, scattered 2B write; tiny)
__global__ __launch_bounds__(256) void k_wt(const float* __restrict__ W,
                                            unsigned short* __restrict__ WT) {
  int idx = blockIdx.x * 256 + threadIdx.x;   // 0..81919
  int k = idx >> 8, c = idx & 255;
  WT[c * 320 + k] = f2bf(W[idx]);
}

// Fused edge GEMM: per 64-edge tile, gather [xi|xj|ea] -> bf16 LDS, then
// gated[spos[e]][:] = bf16( [xi|xj|ea] @ W + b ) via MFMA.
// Block 256 = 4 waves. Wave w owns col-tiles ct = 4w..4w+3 (64 cols), all 64 edges.
__global__ __launch_bounds__(256, 3) void k_gemm1(
    const float* __restrict__ x, const int* __restrict__ ei,
    const float* __restrict__ ea, const unsigned short* __restrict__ WT,
    const float* __restrict__ bias, unsigned short* __restrict__ gated,
    int* __restrict__ cursor, int E) {
  __shared__ unsigned short F[64][328];   // [edge][feat], pad 320->328 (2-way banks)
  __shared__ int ssrc[64], sdst[64], spos[64];
  int tid = threadIdx.x;
  int e0 = blockIdx.x * 64;
  if (tid < 64) {
    int e = e0 + tid;
    int s = 0, d = 0, p = 0;
    if (e < E) {
      s = ei[e]; d = ei[E + e];
      p = atomicAdd(&cursor[s], 1);
    }
    ssrc[tid] = s; sdst[tid] = d; spos[tid] = p;
  }
  __syncthreads();

  // ---- gather + fp32->bf16 convert into F ----
  {
    int q = tid & 31, r2 = tid >> 5;            // 8 rows / iter, 32 float4 per row
    #pragma unroll
    for (int it = 0; it < 8; ++it) {
      int r = r2 + it * 8;
      float4 v = *(const float4*)(x + (size_t)ssrc[r] * 128 + q * 4);
      ushort4 h = {f2bf(v.x), f2bf(v.y), f2bf(v.z), f2bf(v.w)};
      *(ushort4*)&F[r][q * 4] = h;
    }
    #pragma unroll
    for (int it = 0; it < 8; ++it) {
      int r = r2 + it * 8;
      float4 v = *(const float4*)(x + (size_t)sdst[r] * 128 + q * 4);
      ushort4 h = {f2bf(v.x), f2bf(v.y), f2bf(v.z), f2bf(v.w)};
      *(ushort4*)&F[r][128 + q * 4] = h;
    }
    int q2 = tid & 15, r4 = tid >> 4;           // 16 rows / iter, 16 float4 per row
    #pragma unroll
    for (int it = 0; it < 4; ++it) {
      int r = r4 + it * 16;
      int e = e0 + r;
      float4 v = make_float4(0.f, 0.f, 0.f, 0.f);
      if (e < E) v = *(const float4*)(ea + (size_t)e * 64 + q2 * 4);
      ushort4 h = {f2bf(v.x), f2bf(v.y), f2bf(v.z), f2bf(v.w)};
      *(ushort4*)&F[r][256 + q2 * 4] = h;
    }
  }
  __syncthreads();

  // ---- MFMA: D[col][edge] ; A = WT (M=cols), B = F (N=edges) ----
  int w = tid >> 6, l = tid & 63;
  int l15 = l & 15, lg = l >> 4;
  f32x4 acc[4][4] = {};   // [ctl][nt]
  const unsigned short* wtb = WT + (size_t)((w * 4) * 16 + l15) * 320 + lg * 8;
  #pragma unroll 1
  for (int k0 = 0; k0 < 10; ++k0) {
    bf8 bfr[4];
    #pragma unroll
    for (int nt = 0; nt < 4; ++nt) {
      us8 raw = *(const us8*)&F[nt * 16 + l15][k0 * 32 + lg * 8];
      bfr[nt] = __builtin_bit_cast(bf8, raw);
    }
    #pragma unroll
    for (int ctl = 0; ctl < 4; ++ctl) {
      us8 araw = *(const us8*)(wtb + (size_t)ctl * (16 * 320) + k0 * 32);
      bf8 afr = __builtin_bit_cast(bf8, araw);
      #pragma unroll
      for (int nt = 0; nt < 4; ++nt)
        acc[ctl][nt] = __builtin_amdgcn_mfma_f32_16x16x32_bf16(afr, bfr[nt], acc[ctl][nt], 0, 0, 0);
    }
  }

  // ---- epilogue: +bias, ->bf16, scatter rows to CSR slots ----
  #pragma unroll
  for (int ctl = 0; ctl < 4; ++ctl) {
    int col0 = (w * 4 + ctl) * 16 + lg * 4;
    float4 bv = *(const float4*)(bias + col0);
    #pragma unroll
    for (int nt = 0; nt < 4; ++nt) {
      int el = nt * 16 + l15;
      if (e0 + el < E) {
        f32x4 a = acc[ctl][nt];
        ushort4 hv = {f2bf(a[0] + bv.x), f2bf(a[1] + bv.y),
                      f2bf(a[2] + bv.z), f2bf(a[3] + bv.w)};
        *(ushort4*)(gated + (size_t)spos[el] * 256 + col0) = hv;
      }
    }
  }
}

// BN1 stats: streaming sum/sumsq per column over gated [E][256] bf16
__global__ __launch_bounds__(256) void k_bn1stats(const unsigned short* __restrict__ gated,
                                                  float* __restrict__ stats, int E) {
  __shared__ float s_[256], q_[256];
  int tid = threadIdx.x;
  s_[tid] = 0.f; q_[tid] = 0.f;
  __syncthreads();
  int w = tid >> 6, l = tid & 63;
  int c0 = l * 4;
  float s0 = 0, s1 = 0, s2 = 0, s3 = 0, q0 = 0, q1 = 0, q2 = 0, q3 = 0;
  for (int r = blockIdx.x * 4 + w; r < E; r += gridDim.x * 4) {
    ushort4 raw = *(const ushort4*)(gated + (size_t)r * 256 + c0);
    float v0 = bf2f(raw.x), v1 = bf2f(raw.y), v2 = bf2f(raw.z), v3 = bf2f(raw.w);
    s0 += v0; q0 += v0 * v0;
    s1 += v1; q1 += v1 * v1;
    s2 += v2; q2 += v2 * v2;
    s3 += v3; q3 += v3 * v3;
  }
  atomicAdd(&s_[c0], s0);     atomicAdd(&q_[c0], q0);
  atomicAdd(&s_[c0 + 1], s1); atomicAdd(&q_[c0 + 1], q1);
  atomicAdd(&s_[c0 + 2], s2); atomicAdd(&q_[c0 + 2], q2);
  atomicAdd(&s_[c0 + 3], s3); atomicAdd(&q_[c0 + 3], q3);
  __syncthreads();
  atomicAdd(&stats[tid], s_[tid]);
  atomicAdd(&stats[256 + tid], q_[tid]);
}

// finalize BN1: scale/shift per column
__global__ void k_bn1fin(float* __restrict__ stats, const float* __restrict__ g1,
                         const float* __restrict__ b1, float Einv) {
  int j = threadIdx.x;   // 256 threads
  float mu = stats[j] * Einv;
  float var = stats[256 + j] * Einv - mu * mu;
  float s = g1[j] * rsqrtf(var + BN_EPS);
  stats[768 + j] = s;
  stats[1024 + j] = b1[j] - mu * s;
}

// Phase 2: one wave per node: reduce its CSR run of gated rows -> summed (in d_out)
__global__ __launch_bounds__(256) void k_phase2(
    const unsigned short* __restrict__ gated,
    const int* __restrict__ offs, const int* __restrict__ deg,
    const float* __restrict__ stats, float* __restrict__ out, int N) {
  int wid = (blockIdx.x * 256 + threadIdx.x) >> 6;
  int lane = threadIdx.x & 63;
  if (wid >= N) return;
  const float* scale1 = stats + 768;
  const float* shift1 = stats + 1024;
  int c0 = lane * 2;
  float sf0 = scale1[c0], sf1 = scale1[c0 + 1];
  float hf0 = shift1[c0], hf1 = shift1[c0 + 1];
  float sc0 = scale1[128 + c0], sc1 = scale1[128 + c0 + 1];
  float hc0 = shift1[128 + c0], hc1 = shift1[128 + c0 + 1];
  int st = offs[wid], d = deg[wid];
  const unsigned short* rowp = gated + (size_t)st * 256;
  float a0 = 0.f, a1 = 0.f;
  for (int i = 0; i < d; ++i) {
    unsigned int fw = *(const unsigned int*)(rowp + c0);
    unsigned int cw = *(const unsigned int*)(rowp + 128 + c0);
    float f0 = bf2f((unsigned short)(fw & 0xFFFFu)) * sf0 + hf0;
    float f1 = bf2f((unsigned short)(fw >> 16)) * sf1 + hf1;
    float q0 = bf2f((unsigned short)(cw & 0xFFFFu)) * sc0 + hc0;
    float q1 = bf2f((unsigned short)(cw >> 16)) * sc1 + hc1;
    a0 += sigmoidf_(f0) * softplusf_(q0);
    a1 += sigmoidf_(f1) * softplusf_(q1);
    rowp += 256;
  }
  *(float2*)(out + (size_t)wid * 128 + c0) = make_float2(a0, a1);
}

// BN2 stats over summed (= d_out)
__global__ __launch_bounds__(256) void k_bn2stats(const float* __restrict__ out,
                                                  float* __restrict__ stats, int N) {
  float* sum2 = stats + 512;
  float* sq2 = stats + 640;
  __shared__ float s_[128], q_[128];
  int c = threadIdx.x & 127, h = threadIdx.x >> 7;
  float s = 0.f, q = 0.f;
  for (int r = blockIdx.x * 2 + h; r < N; r += gridDim.x * 2) {
    float v = out[(size_t)r * 128 + c];
    s += v; q += v * v;
  }
  if (h == 0) { s_[c] = s; q_[c] = q; }
  __syncthreads();
  if (h == 1) { s_[c] += s; q_[c] += q; }
  __syncthreads();
  if (h == 0) { atomicAdd(&sum2[c], s_[c]); atomicAdd(&sq2[c], q_[c]); }
}

// BN2 normalize in place
__global__ __launch_bounds__(256) void k_bn2norm(float* __restrict__ out,
                                                 const float* __restrict__ stats,
                                                 const float* __restrict__ g2,
                                                 const float* __restrict__ b2, int N) {
  const float* sum2 = stats + 512;
  const float* sq2 = stats + 640;
  float Ninv = 1.0f / (float)N;
  size_t total = (size_t)N * 32;   // float4 count
  for (size_t i = (size_t)blockIdx.x * blockDim.x + threadIdx.x; i < total;
       i += (size_t)gridDim.x * blockDim.x) {
    float4 v = *((const float4*)out + i);
    int c = (int)((i & 31) << 2);
    float r[4] = {v.x, v.y, v.z, v.w};
    #pragma unroll
    for (int j = 0; j < 4; ++j) {
      float mu = sum2[c + j] * Ninv;
      float var = sq2[c + j] * Ninv - mu * mu;
      float sc = g2[c + j] * rsqrtf(var + BN_EPS);
      r[j] = (r[j] - mu) * sc + b2[c + j];
    }
    *((float4*)out + i) = make_float4(r[0], r[1], r[2], r[3]);
  }
}

// ---------- launch ----------
extern "C" void kernel_launch(void* const* d_in, const int* in_sizes, int n_in,
                              void* d_out, int out_size, void* d_ws, size_t ws_size,
                              hipStream_t stream) {
  (void)n_in; (void)out_size;
  const float* x  = (const float*)d_in[0];
  const int*   ei = (const int*)d_in[1];
  const float* ea = (const float*)d_in[2];
  const float* W  = (const float*)d_in[3];
  const float* b  = (const float*)d_in[4];
  const float* g1 = (const float*)d_in[5];
  const float* b1 = (const float*)d_in[6];
  const float* g2 = (const float*)d_in[7];
  const float* b2 = (const float*)d_in[8];
  int N = in_sizes[0] / 128;
  int E = in_sizes[1] / 2;
  float* out = (float*)d_out;

  // ws layout
  char* base = (char*)d_ws;
  size_t off = 0;
  auto take = [&](size_t bytes) {
    size_t o = off;
    off = (off + bytes + 255) & ~(size_t)255;
    return o;
  };
  size_t oWT     = take((size_t)256 * 320 * sizeof(unsigned short));
  size_t oGated  = take((size_t)E * 256 * sizeof(unsigned short));
  size_t oDeg    = take((size_t)N * sizeof(int));
  size_t oOffs   = take((size_t)N * sizeof(int));
  size_t oCur    = take((size_t)N * sizeof(int));
  size_t oStats  = take(2048 * sizeof(float));
  if (off > ws_size) return;

  unsigned short* WT = (unsigned short*)(base + oWT);
  unsigned short* gated = (unsigned short*)(base + oGated);
  int* deg = (int*)(base + oDeg);
  int* offs = (int*)(base + oOffs);
  int* cursor = (int*)(base + oCur);
  float* stats = (float*)(base + oStats);

  k_zero<<<256, 256, 0, stream>>>(deg, stats, N);
  k_deg<<<(E + 255) / 256, 256, 0, stream>>>(ei, deg, E);
  k_scan<<<1, 1024, 0, stream>>>(deg, offs, cursor, N);
  k_wt<<<320, 256, 0, stream>>>(W, WT);
  k_gemm1<<<(E + 63) / 64, 256, 0, stream>>>(x, ei, ea, WT, b, gated, cursor, E);
  k_bn1stats<<<1024, 256, 0, stream>>>(gated, stats, E);
  k_bn1fin<<<1, 256, 0, stream>>>(stats, g1, b1, 1.0f / (float)E);
  k_phase2<<<(N + 3) / 4, 256, 0, stream>>>(gated, offs, deg, stats, out, N);
  k_bn2stats<<<512, 256, 0, stream>>>(out, stats, N);
  k_bn2norm<<<1024, 256, 0, stream>>>(out, stats, g2, b2, N);
}